// Round 5
// baseline (939.060 us; speedup 1.0000x reference)
//
#include <hip/hip_runtime.h>
#include <math.h>

#define NN 27
#define HID 128
#define HS 132           // padded row stride (floats) for h1/H: 4-row groups land 16 banks apart -> free 2-way
#define SITERS 20

typedef float v4 __attribute__((ext_vector_type(4)));

// ---------------- Kernel 1: features + MLP + scores -> exp(log_alpha) into d_out ----------------
// block = 128 threads, one batch element per block. One LDS buffer, sequential lifetimes:
//   [P0] A staging (729 f) -> [P2] h1 (28 x HS) -> [P5a] normalized H (27 x HS)
// Register-pressure history: R2 arg=3 -> 84-cap spill disaster; R3 cap=128 + full unroll ->
// pipeliner spilled 4 GB; R4 cap=128 + unroll 1 -> VGPR 52, no spill, 772 us @ VALUBusy 54%.
// R5: keep cap + unroll discipline, add explicit W2 register double-buffer (ILP covers the
// ~200-cyc L2 latency that unroll-1's per-iteration vmcnt(0) exposed).
__global__ __launch_bounds__(128, 2) void k1_mlp(
    const float* __restrict__ A, const float* __restrict__ m,
    const float* __restrict__ tau_r,
    const float* __restrict__ ln1g, const float* __restrict__ ln1b,
    const float* __restrict__ W1, const float* __restrict__ b1,
    const float* __restrict__ W2, const float* __restrict__ b2,
    const float* __restrict__ ln2g, const float* __restrict__ ln2b,
    const float* __restrict__ protos, float* __restrict__ out)
{
    __shared__ __align__(16) float sBuf[28 * HS];       // 14.8 KB unified buffer
    __shared__ __align__(16) float sFeat[NN * 4 + 4];

    const int b   = blockIdx.x;
    const int tid = threadIdx.x;
    const float* Ab = A + (size_t)b * (NN * NN);

    // ---- P0: stage A (729 floats) ----
    float* sA = sBuf;
    for (int i = tid; i < NN * NN; i += 128) sA[i] = Ab[i];
    __syncthreads();

    // ---- P1: per-row features [log1p(rowsum), top1_offdiag, top2_offdiag, m], then LN1 ----
    if (tid < NN) {
        const int n = tid;
        float sum = 0.f, m1 = -1e30f, m2 = -1e30f;
        #pragma unroll
        for (int j = 0; j < NN; ++j) {
            float a = sA[n * NN + j];
            sum += a;
            float v = (j == n) ? 0.f : a;
            float nm1 = fmaxf(m1, v);
            m2 = fmaxf(m2, fminf(m1, v));
            m1 = nm1;
        }
        float f0 = log1pf(sum), f1 = m1, f2 = m2, f3 = m[(size_t)b * NN + n];
        float mu = 0.25f * (f0 + f1 + f2 + f3);
        float d0 = f0 - mu, d1 = f1 - mu, d2 = f2 - mu, d3 = f3 - mu;
        float var = 0.25f * (d0*d0 + d1*d1 + d2*d2 + d3*d3);
        float rs  = rsqrtf(var + 1e-5f);
        sFeat[n*4 + 0] = d0 * rs * ln1g[0] + ln1b[0];
        sFeat[n*4 + 1] = d1 * rs * ln1g[1] + ln1b[1];
        sFeat[n*4 + 2] = d2 * rs * ln1g[2] + ln1b[2];
        sFeat[n*4 + 3] = d3 * rs * ln1g[3] + ln1b[3];
    }
    __syncthreads();

    // ---- P2: h1 = relu(featLN @ W1 + b1) into sBuf (stride HS); zero pad row 27 ----
    {
        const float w0 = W1[tid], w1 = W1[HID + tid], w2 = W1[2*HID + tid], w3 = W1[3*HID + tid];
        const float bb = b1[tid];
        #pragma unroll 9
        for (int n = 0; n < NN; ++n) {
            v4 f = *(const v4*)&sFeat[n * 4];
            float v = fmaf(f[0], w0, fmaf(f[1], w1, fmaf(f[2], w2, fmaf(f[3], w3, bb))));
            sBuf[n * HS + tid] = fmaxf(v, 0.f);
        }
        sBuf[27 * HS + tid] = 0.f;
    }
    __syncthreads();

    // ---- P3: h2 = h1 @ W2 + b2. Register tile: 4 rows x 8 cols per thread. ----
    // W2 loads double-buffered in registers: prefetch k+4 while computing k.
    // #pragma unroll 2 makes the parity index compile-time (no v_mov copies) while
    // bounding the pipeliner's live-load window at 2 iterations (~122 live regs < 128 cap).
    const int tcol = tid & 15, g = tid >> 4;
    const int n0 = (g < 7 ? g : 6) * 4;
    const int t0 = tcol * 8;
    v4 acc[4][2];
    {
        v4 ba = *(const v4*)&b2[t0], bb2 = *(const v4*)&b2[t0 + 4];
        #pragma unroll
        for (int nn = 0; nn < 4; ++nn) { acc[nn][0] = ba; acc[nn][1] = bb2; }

        const float* w2t = W2 + t0;
        v4 wa[2][4], wb[2][4];
        #pragma unroll
        for (int kk = 0; kk < 4; ++kk) {
            wa[0][kk] = *(const v4*)&w2t[kk * HID];
            wb[0][kk] = *(const v4*)&w2t[kk * HID + 4];
        }
        #pragma unroll 2
        for (int k = 0; k < HID; k += 4) {
            const int p  = (k >> 2) & 1;
            const int kn = (k + 4) & (HID - 1);          // clamp: last iter re-reads row 0 (harmless)
            const float* wrn = w2t + kn * HID;
            #pragma unroll
            for (int kk = 0; kk < 4; ++kk) {
                wa[p ^ 1][kk] = *(const v4*)&wrn[kk * HID];
                wb[p ^ 1][kk] = *(const v4*)&wrn[kk * HID + 4];
            }
            v4 h[4];
            #pragma unroll
            for (int nn = 0; nn < 4; ++nn) h[nn] = *(const v4*)&sBuf[(n0 + nn) * HS + k];
            #pragma unroll
            for (int kk = 0; kk < 4; ++kk) {
                #pragma unroll
                for (int nn = 0; nn < 4; ++nn) {
                    float hv = h[nn][kk];
                    acc[nn][0] += hv * wa[p][kk];
                    acc[nn][1] += hv * wb[p][kk];
                }
            }
        }
    }
    __syncthreads();   // all h1 reads done; sBuf can be overwritten with H

    // ---- P4: LN2 stats in-register: reduce over the 16 lanes owning each row ----
    {
        v4 g2a = *(const v4*)&ln2g[t0], g2b = *(const v4*)&ln2g[t0 + 4];
        v4 ba2 = *(const v4*)&ln2b[t0], bb3 = *(const v4*)&ln2b[t0 + 4];
        #pragma unroll
        for (int nn = 0; nn < 4; ++nn) {
            v4 a0 = acc[nn][0], a1 = acc[nn][1];
            float s  = a0[0]+a0[1]+a0[2]+a0[3] + a1[0]+a1[1]+a1[2]+a1[3];
            float ss = a0[0]*a0[0]+a0[1]*a0[1]+a0[2]*a0[2]+a0[3]*a0[3]
                     + a1[0]*a1[0]+a1[1]*a1[1]+a1[2]*a1[2]+a1[3]*a1[3];
            #pragma unroll
            for (int mask = 1; mask <= 8; mask <<= 1) {
                s  += __shfl_xor(s,  mask);
                ss += __shfl_xor(ss, mask);
            }
            float mu  = s * (1.0f / HID);
            float var = ss * (1.0f / HID) - mu * mu;
            float rs  = rsqrtf(var + 1e-5f);
            int n = n0 + nn;
            if (n < NN) {
                *(v4*)&sBuf[n * HS + t0]     = (a0 - mu) * rs * g2a + ba2;
                *(v4*)&sBuf[n * HS + t0 + 4] = (a1 - mu) * rs * g2b + bb3;
            }
        }
    }
    __syncthreads();

    // ---- P5: out[i][j] = exp((H[j] . protos[i]) / tau)  (linear-domain P for Sinkhorn) ----
    const float inv_tau = 1.0f / tau_r[0];
    if (tid < 126) {
        const int ig = tid / 9, jg = tid - ig * 9;
        const int i0 = ig * 2, j0 = jg * 3;
        const int i1 = i0 + 1;
        const int i1c = (i1 < NN) ? i1 : (NN - 1);
        v4 va[2][3];
        #pragma unroll
        for (int ii = 0; ii < 2; ++ii)
            #pragma unroll
            for (int jj = 0; jj < 3; ++jj) va[ii][jj] = (v4)(0.f);
        #pragma unroll 2
        for (int k = 0; k < HID; k += 4) {
            v4 hq0 = *(const v4*)&sBuf[(j0 + 0) * HS + k];
            v4 hq1 = *(const v4*)&sBuf[(j0 + 1) * HS + k];
            v4 hq2 = *(const v4*)&sBuf[(j0 + 2) * HS + k];
            v4 pa  = *(const v4*)&protos[i0  * HID + k];
            v4 pb  = *(const v4*)&protos[i1c * HID + k];
            va[0][0] += hq0 * pa; va[0][1] += hq1 * pa; va[0][2] += hq2 * pa;
            va[1][0] += hq0 * pb; va[1][1] += hq1 * pb; va[1][2] += hq2 * pb;
        }
        float* ob = out + (size_t)b * (NN * NN);
        #pragma unroll
        for (int ii = 0; ii < 2; ++ii) {
            int i = i0 + ii;
            if (i < NN) {
                #pragma unroll
                for (int jj = 0; jj < 3; ++jj) {
                    v4 t = va[ii][jj];
                    ob[i * NN + (j0 + jj)] = __expf((t[0] + t[1] + t[2] + t[3]) * inv_tau);
                }
            }
        }
    }
}

// ---------------- Kernel 2: LINEAR-domain Sinkhorn (20 iters), in-place on P ----------------
// block = 256 threads = 4 waves; 2 elements per wave (32-lane halves), wave_barrier only.
// Column scale factors c[] are deferred into the next row pass (no column writes).
#define ES 800   // element stride in LDS floats: 27 rows x 28 + c[28] at offset 756
__global__ __launch_bounds__(256) void k2_sinkhorn(float* __restrict__ la, int B)
{
    __shared__ __align__(16) float sLa[8 * ES];

    const int w = threadIdx.x >> 6;
    const int l = threadIdx.x & 63;
    const int half = l >> 5, r = l & 31;
    const int eb = blockIdx.x * 8 + w * 2;
    if (eb >= B) return;
    const int nel = (B - eb >= 2) ? 2 : 1;

    float* sw = sLa + (w * 2) * ES;
    const size_t gbase = (size_t)eb * (NN * NN);

    // load P (stride 27 -> 28), init c = 1 and pad col = 0
    for (int idx = l; idx < nel * NN * NN; idx += 64) {
        int e = (idx >= NN * NN) ? 1 : 0;
        int p = idx - e * (NN * NN);
        int row = p / NN, col = p - row * NN;
        sw[e * ES + row * 28 + col] = la[gbase + idx];
    }
    for (int idx = l; idx < nel * 28; idx += 64) {
        int e = (idx >= 28) ? 1 : 0;
        int j = idx - e * 28;
        sw[e * ES + 756 + j] = 1.f;
        if (j < NN) sw[e * ES + j * 28 + NN] = 0.f;
    }
    __builtin_amdgcn_wave_barrier();

    float* se = sw + half * ES;
    float* ce = se + 756;
    const bool act = (r < NN) && (half < nel);

    for (int it = 0; it < SITERS; ++it) {
        // row pass: apply pending col factors, row-normalize. Lane r owns row r (contiguous).
        if (act) {
            float* rp = se + r * 28;
            v4 x[7], cc[7];
            #pragma unroll
            for (int qi = 0; qi < 7; ++qi) { x[qi] = *(const v4*)&rp[qi * 4]; cc[qi] = *(const v4*)&ce[qi * 4]; }
            #pragma unroll
            for (int qi = 0; qi < 7; ++qi) x[qi] *= cc[qi];
            float s = 0.f;
            #pragma unroll
            for (int qi = 0; qi < 6; ++qi) s += x[qi][0] + x[qi][1] + x[qi][2] + x[qi][3];
            s += x[6][0] + x[6][1] + x[6][2];
            float rho = 1.0f / s;
            #pragma unroll
            for (int qi = 0; qi < 7; ++qi) *(v4*)&rp[qi * 4] = x[qi] * rho;
        }
        __builtin_amdgcn_wave_barrier();
        // col pass: compute new col factors only (no writes to the matrix). Lane r owns col r.
        if (act) {
            const float* cp = se + r;
            float s = 0.f;
            #pragma unroll
            for (int i = 0; i < NN; ++i) s += cp[i * 28];
            ce[r] = 1.0f / s;
        }
        __builtin_amdgcn_wave_barrier();
    }

    // final store: apply pending col factors, coalesced
    for (int idx = l; idx < nel * NN * NN; idx += 64) {
        int e = (idx >= NN * NN) ? 1 : 0;
        int p = idx - e * (NN * NN);
        int row = p / NN, col = p - row * NN;
        la[gbase + idx] = sw[e * ES + row * 28 + col] * sw[e * ES + 756 + col];
    }
}

extern "C" void kernel_launch(void* const* d_in, const int* in_sizes, int n_in,
                              void* d_out, int out_size, void* d_ws, size_t ws_size,
                              hipStream_t stream) {
    const float* A      = (const float*)d_in[0];
    const float* m      = (const float*)d_in[1];
    const float* tau_r  = (const float*)d_in[2];
    const float* ln1g   = (const float*)d_in[3];
    const float* ln1b   = (const float*)d_in[4];
    const float* W1     = (const float*)d_in[5];
    const float* b1     = (const float*)d_in[6];
    const float* W2     = (const float*)d_in[7];
    const float* b2     = (const float*)d_in[8];
    const float* ln2g   = (const float*)d_in[9];
    const float* ln2b   = (const float*)d_in[10];
    const float* protos = (const float*)d_in[11];
    float* out = (float*)d_out;

    const int B = in_sizes[0] / (NN * NN);

    k1_mlp<<<B, 128, 0, stream>>>(A, m, tau_r, ln1g, ln1b, W1, b1, W2, b2,
                                  ln2g, ln2b, protos, out);
    const int blocks2 = (B + 7) / 8;
    k2_sinkhorn<<<blocks2, 256, 0, stream>>>(out, B);
}

// Round 6
// 711.769 us; speedup vs baseline: 1.3193x; 1.3193x over previous
//
#include <hip/hip_runtime.h>
#include <math.h>

#define NN 27
#define HID 128
#define SITERS 20
#define H1S 136          // f16 row stride for h1/H in LDS (272 B = 16B-aligned, bank-spread)

typedef float    v4    __attribute__((ext_vector_type(4)));
typedef _Float16 f16x8 __attribute__((ext_vector_type(8)));

// ---------------- Kernel 0: pre-swizzle W2 / protos into f16 MFMA fragment order ----------------
// B-frag (16x16x32): lane l holds B[k=kt*32+(l>>4)*8+j][n=nt*16+(l&15)], j=0..7 -> one 16B load/lane.
// A-frag:            lane l holds A[m=mt*16+(l&15)][k=kt*32+(l>>4)*8+j]          (m120-verified layout)
__global__ void k0_prep(const float* __restrict__ W2, const float* __restrict__ protos,
                        _Float16* __restrict__ Bsw, _Float16* __restrict__ Asw)
{
    int t0 = blockIdx.x * 256 + threadIdx.x;
    for (int idx = t0; idx < 4*8*64*8; idx += 8*256) {       // W2: kt(4) x nt(8) x lane x 8
        int j = idx & 7, l = (idx >> 3) & 63, nt = (idx >> 9) & 7, kt = idx >> 12;
        int k = kt*32 + (l >> 4)*8 + j, n = nt*16 + (l & 15);
        Bsw[idx] = (_Float16)W2[k*HID + n];
    }
    for (int idx = t0; idx < 2*4*64*8; idx += 8*256) {       // protos: mt(2) x kt(4) x lane x 8
        int j = idx & 7, l = (idx >> 3) & 63, kt = (idx >> 9) & 3, mt = idx >> 11;
        int k = kt*32 + (l >> 4)*8 + j, mm = mt*16 + (l & 15);
        Asw[idx] = (mm < NN) ? (_Float16)protos[mm*HID + k] : (_Float16)0.0f;
    }
}

// ---------------- Kernel 1: features + MLP(MFMA) + scores(MFMA) -> P into d_out ----------------
// block = 128 threads = 2 waves; wave w owns M-tile w (rows w*16..w*16+15) of both GEMMs.
// History: R2 cap84 spill; R3 cap128+full-unroll spill; R4 unroll1 -> 772us VALU-bound (W2 8x
// re-read, 4096 FMA/thread); R5 reg-dbuf defeated by scheduler. R6: MFMA rewrite (f16 operands,
// fp32 acc): 40 MFMA/wave replaces ~4900 FMA/thread, W2 traffic/block 512KB -> 64KB.
__global__ __launch_bounds__(128, 2) void k1_mlp(
    const float* __restrict__ A, const float* __restrict__ m,
    const float* __restrict__ tau_r,
    const float* __restrict__ ln1g, const float* __restrict__ ln1b,
    const float* __restrict__ W1, const float* __restrict__ b1,
    const float* __restrict__ b2,
    const float* __restrict__ ln2g, const float* __restrict__ ln2b,
    const _Float16* __restrict__ Bsw, const _Float16* __restrict__ Asw,
    float* __restrict__ out)
{
    __shared__ __align__(16) float    sA[NN*NN + 3];
    __shared__ __align__(16) float    sFeat[NN*4 + 4];
    __shared__ __align__(16) _Float16 sH1[32 * H1S];   // h1 f16, rows 27..31 zero
    __shared__ __align__(16) _Float16 sH[32 * H1S];    // normalized H f16

    const int b   = blockIdx.x;
    const int tid = threadIdx.x;
    const int l = tid & 63, w = tid >> 6;
    const int c = l & 15, g = l >> 4;
    const float* Ab = A + (size_t)b * (NN * NN);

    // ---- P0: stage A ----
    for (int i = tid; i < NN * NN; i += 128) sA[i] = Ab[i];
    __syncthreads();

    // ---- P1: features [log1p(rowsum), top1_offdiag, top2_offdiag, m] + LN1 ----
    if (tid < NN) {
        const int n = tid;
        float sum = 0.f, m1 = -1e30f, m2 = -1e30f;
        #pragma unroll
        for (int j = 0; j < NN; ++j) {
            float a = sA[n * NN + j];
            sum += a;
            float v = (j == n) ? 0.f : a;
            float nm1 = fmaxf(m1, v);
            m2 = fmaxf(m2, fminf(m1, v));
            m1 = nm1;
        }
        float f0 = log1pf(sum), f1 = m1, f2 = m2, f3 = m[(size_t)b * NN + n];
        float mu = 0.25f * (f0 + f1 + f2 + f3);
        float d0 = f0 - mu, d1 = f1 - mu, d2 = f2 - mu, d3 = f3 - mu;
        float var = 0.25f * (d0*d0 + d1*d1 + d2*d2 + d3*d3);
        float rs  = rsqrtf(var + 1e-5f);
        sFeat[n*4 + 0] = d0 * rs * ln1g[0] + ln1b[0];
        sFeat[n*4 + 1] = d1 * rs * ln1g[1] + ln1b[1];
        sFeat[n*4 + 2] = d2 * rs * ln1g[2] + ln1b[2];
        sFeat[n*4 + 3] = d3 * rs * ln1g[3] + ln1b[3];
    }
    __syncthreads();

    // ---- P2: h1 = relu(featLN @ W1 + b1) -> sH1 as f16; zero pad rows 27..31 ----
    {
        const float w0 = W1[tid], w1 = W1[HID + tid], w2 = W1[2*HID + tid], w3 = W1[3*HID + tid];
        const float bb = b1[tid];
        #pragma unroll 9
        for (int n = 0; n < NN; ++n) {
            v4 f = *(const v4*)&sFeat[n * 4];
            float v = fmaf(f[0], w0, fmaf(f[1], w1, fmaf(f[2], w2, fmaf(f[3], w3, bb))));
            sH1[n * H1S + tid] = (_Float16)fmaxf(v, 0.f);
        }
        #pragma unroll
        for (int n = NN; n < 32; ++n) sH1[n * H1S + tid] = (_Float16)0.f;
    }
    __syncthreads();

    // ---- P3: h2 = h1 @ W2 + b2 via MFMA. Wave w: rows w*16..+15, all 8 col-tiles. ----
    f16x8 af[4];
    #pragma unroll
    for (int kt = 0; kt < 4; ++kt)
        af[kt] = *(const f16x8*)&sH1[(w*16 + c) * H1S + kt*32 + g*8];

    v4 acc[8];
    #pragma unroll
    for (int nt = 0; nt < 8; ++nt) acc[nt] = (v4)(0.f);

    {
        const f16x8* Bv = (const f16x8*)Bsw;
        #pragma unroll 1            // bound live B-frags to one kt (32 regs) -> no spill
        for (int kt = 0; kt < 4; ++kt) {
            #pragma unroll
            for (int nt = 0; nt < 8; ++nt) {
                f16x8 bf = Bv[(kt*8 + nt)*64 + l];
                acc[nt] = __builtin_amdgcn_mfma_f32_16x16x32_f16(af[kt], bf, acc[nt], 0, 0, 0);
            }
        }
    }

    // ---- P4: +bias, LN2 in C-layout (lane: rows w*16+4g+r, col nt*16+c), shfl over 16 lanes ----
    {
        float b2v[8], g2v[8], bbv[8];
        #pragma unroll
        for (int nt = 0; nt < 8; ++nt) {
            int col = nt*16 + c;
            b2v[nt] = b2[col]; g2v[nt] = ln2g[col]; bbv[nt] = ln2b[col];
        }
        #pragma unroll
        for (int r = 0; r < 4; ++r) {
            float s = 0.f, ss = 0.f;
            #pragma unroll
            for (int nt = 0; nt < 8; ++nt) {
                float v = acc[nt][r] + b2v[nt];
                acc[nt][r] = v;
                s += v; ss += v * v;
            }
            #pragma unroll
            for (int mask = 1; mask <= 8; mask <<= 1) {
                s  += __shfl_xor(s,  mask);
                ss += __shfl_xor(ss, mask);
            }
            float mu  = s * (1.0f / HID);
            float var = ss * (1.0f / HID) - mu * mu;
            float rs  = rsqrtf(var + 1e-5f);
            int row = w*16 + 4*g + r;
            #pragma unroll
            for (int nt = 0; nt < 8; ++nt) {
                float hv = (acc[nt][r] - mu) * rs * g2v[nt] + bbv[nt];
                sH[row * H1S + nt*16 + c] = (_Float16)hv;
            }
        }
    }
    __syncthreads();   // all H rows written (both waves) before P5 B-frag reads

    // ---- P5: out[i][j] = exp((protos[i] . H[j]) / tau) via MFMA. Wave w: i-tile w. ----
    {
        const f16x8* Av = (const f16x8*)Asw;
        f16x8 pa[4];
        #pragma unroll
        for (int kt = 0; kt < 4; ++kt) pa[kt] = Av[(w*4 + kt)*64 + l];

        v4 acc2[2];
        acc2[0] = (v4)(0.f); acc2[1] = (v4)(0.f);
        #pragma unroll
        for (int kt = 0; kt < 4; ++kt) {
            f16x8 b0 = *(const f16x8*)&sH[(c)      * H1S + kt*32 + g*8];
            f16x8 b1f = *(const f16x8*)&sH[(16 + c) * H1S + kt*32 + g*8];
            acc2[0] = __builtin_amdgcn_mfma_f32_16x16x32_f16(pa[kt], b0,  acc2[0], 0, 0, 0);
            acc2[1] = __builtin_amdgcn_mfma_f32_16x16x32_f16(pa[kt], b1f, acc2[1], 0, 0, 0);
        }

        const float inv_tau = 1.0f / tau_r[0];
        float* ob = out + (size_t)b * (NN * NN);
        #pragma unroll
        for (int nt2 = 0; nt2 < 2; ++nt2) {
            int j = nt2*16 + c;
            if (j < NN) {
                #pragma unroll
                for (int r = 0; r < 4; ++r) {
                    int i = w*16 + 4*g + r;
                    if (i < NN) ob[i * NN + j] = __expf(acc2[nt2][r] * inv_tau);
                }
            }
        }
    }
}

// ---------------- Kernel 2: LINEAR-domain Sinkhorn (20 iters), in-place on P ----------------
#define ES 800   // element stride in LDS floats: 27 rows x 28 + c[28] at offset 756
__global__ __launch_bounds__(256) void k2_sinkhorn(float* __restrict__ la, int B)
{
    __shared__ __align__(16) float sLa[8 * ES];

    const int w = threadIdx.x >> 6;
    const int l = threadIdx.x & 63;
    const int half = l >> 5, r = l & 31;
    const int eb = blockIdx.x * 8 + w * 2;
    if (eb >= B) return;
    const int nel = (B - eb >= 2) ? 2 : 1;

    float* sw = sLa + (w * 2) * ES;
    const size_t gbase = (size_t)eb * (NN * NN);

    for (int idx = l; idx < nel * NN * NN; idx += 64) {
        int e = (idx >= NN * NN) ? 1 : 0;
        int p = idx - e * (NN * NN);
        int row = p / NN, col = p - row * NN;
        sw[e * ES + row * 28 + col] = la[gbase + idx];
    }
    for (int idx = l; idx < nel * 28; idx += 64) {
        int e = (idx >= 28) ? 1 : 0;
        int j = idx - e * 28;
        sw[e * ES + 756 + j] = 1.f;
        if (j < NN) sw[e * ES + j * 28 + NN] = 0.f;
    }
    __builtin_amdgcn_wave_barrier();

    float* se = sw + half * ES;
    float* ce = se + 756;
    const bool act = (r < NN) && (half < nel);

    for (int it = 0; it < SITERS; ++it) {
        if (act) {
            float* rp = se + r * 28;
            v4 x[7], cc[7];
            #pragma unroll
            for (int qi = 0; qi < 7; ++qi) { x[qi] = *(const v4*)&rp[qi * 4]; cc[qi] = *(const v4*)&ce[qi * 4]; }
            #pragma unroll
            for (int qi = 0; qi < 7; ++qi) x[qi] *= cc[qi];
            float s = 0.f;
            #pragma unroll
            for (int qi = 0; qi < 6; ++qi) s += x[qi][0] + x[qi][1] + x[qi][2] + x[qi][3];
            s += x[6][0] + x[6][1] + x[6][2];
            float rho = 1.0f / s;
            #pragma unroll
            for (int qi = 0; qi < 7; ++qi) *(v4*)&rp[qi * 4] = x[qi] * rho;
        }
        __builtin_amdgcn_wave_barrier();
        if (act) {
            const float* cp = se + r;
            float s = 0.f;
            #pragma unroll
            for (int i = 0; i < NN; ++i) s += cp[i * 28];
            ce[r] = 1.0f / s;
        }
        __builtin_amdgcn_wave_barrier();
    }

    for (int idx = l; idx < nel * NN * NN; idx += 64) {
        int e = (idx >= NN * NN) ? 1 : 0;
        int p = idx - e * (NN * NN);
        int row = p / NN, col = p - row * NN;
        la[gbase + idx] = sw[e * ES + row * 28 + col] * sw[e * ES + 756 + col];
    }
}

extern "C" void kernel_launch(void* const* d_in, const int* in_sizes, int n_in,
                              void* d_out, int out_size, void* d_ws, size_t ws_size,
                              hipStream_t stream) {
    const float* A      = (const float*)d_in[0];
    const float* m      = (const float*)d_in[1];
    const float* tau_r  = (const float*)d_in[2];
    const float* ln1g   = (const float*)d_in[3];
    const float* ln1b   = (const float*)d_in[4];
    const float* W1     = (const float*)d_in[5];
    const float* b1     = (const float*)d_in[6];
    const float* W2     = (const float*)d_in[7];
    const float* b2     = (const float*)d_in[8];
    const float* ln2g   = (const float*)d_in[9];
    const float* ln2b   = (const float*)d_in[10];
    const float* protos = (const float*)d_in[11];
    float* out = (float*)d_out;

    const int B = in_sizes[0] / (NN * NN);

    _Float16* Bsw = (_Float16*)d_ws;                         // 16384 f16 = 32 KB
    _Float16* Asw = (_Float16*)((char*)d_ws + 32768);        //  4096 f16 =  8 KB

    k0_prep<<<8, 256, 0, stream>>>(W2, protos, Bsw, Asw);
    k1_mlp<<<B, 128, 0, stream>>>(A, m, tau_r, ln1g, ln1b, W1, b1, b2,
                                  ln2g, ln2b, Bsw, Asw, out);
    const int blocks2 = (B + 7) / 8;
    k2_sinkhorn<<<blocks2, 256, 0, stream>>>(out, B);
}